// Round 1
// baseline (597.518 us; speedup 1.0000x reference)
//
#include <hip/hip_runtime.h>

#define LN_EPS 1e-5f

constexpr int DIM   = 768;
constexpr int R     = 4;            // rows per wave
constexpr int WAVES = 8;            // waves per block
constexpr int BLOCK = WAVES * 64;   // 512 threads

__launch_bounds__(BLOCK, 1)
__global__ void fused_concat_linear(const float* __restrict__ feat,
                                    const float* __restrict__ W_int,
                                    const float* __restrict__ W_stim,
                                    const float* __restrict__ trans,
                                    const float* __restrict__ ln_w,
                                    const float* __restrict__ ln_b,
                                    const float* __restrict__ W_out,
                                    const float* __restrict__ b_out,
                                    float* __restrict__ out,
                                    int B)
{
    // ---- LDS staging: all weights (~59 KB) ----
    __shared__ float sW[2 * 9 * DIM];   // [0..9*DIM): W_int, [9*DIM..): W_stim
    __shared__ float sTr[729];          // trans[a][j][k]
    __shared__ float sWo[162];          // W_out[k][i], row-major [9][18]
    __shared__ float sBo[9];
    __shared__ float sLw[9];
    __shared__ float sLb[9];

    const int tid = threadIdx.x;
    {
        const float4* srcI = (const float4*)W_int;
        const float4* srcS = (const float4*)W_stim;
        float4* dst = (float4*)sW;
        constexpr int NW4 = (9 * DIM) / 4;   // 1728 float4 per matrix
        for (int i = tid; i < NW4; i += BLOCK) {
            dst[i]       = srcI[i];
            dst[i + NW4] = srcS[i];
        }
        for (int i = tid; i < 729; i += BLOCK) sTr[i] = trans[i];
        if (tid < 162) sWo[tid] = W_out[tid];
        if (tid < 9) { sBo[tid] = b_out[tid]; sLw[tid] = ln_w[tid]; sLb[tid] = ln_b[tid]; }
    }
    __syncthreads();

    const int lane = tid & 63;
    const int wave = tid >> 6;
    const int r0 = (blockIdx.x * WAVES + wave) * R;

    int rows[R];
#pragma unroll
    for (int r = 0; r < R; ++r) rows[r] = min(r0 + r, B - 1);

    float acc_i[R][9];   // partial dots vs W_int  (feat[:,0,:]) -> "last"
    float acc_s[R][9];   // partial dots vs W_stim (feat[:,1,:]) -> "this"
#pragma unroll
    for (int r = 0; r < R; ++r)
#pragma unroll
        for (int a = 0; a < 9; ++a) { acc_i[r][a] = 0.f; acc_s[r][a] = 0.f; }

    // ---- main streaming loop: 3 iterations cover 768 floats (64 lanes x float4) ----
#pragma unroll
    for (int t = 0; t < 3; ++t) {
        const int base = t * 256 + lane * 4;   // float index within a 768-row
        float4 f0[R], f1[R];
#pragma unroll
        for (int r = 0; r < R; ++r) {
            const float* p = feat + (size_t)rows[r] * (2 * DIM);
            f0[r] = *(const float4*)(p + base);
            f1[r] = *(const float4*)(p + DIM + base);
        }
#pragma unroll
        for (int a = 0; a < 9; ++a) {
            const float4 wi = *(const float4*)(sW + a * DIM + base);
            const float4 ws = *(const float4*)(sW + 9 * DIM + a * DIM + base);
#pragma unroll
            for (int r = 0; r < R; ++r) {
                float ai = acc_i[r][a];
                ai = fmaf(f0[r].x, wi.x, ai);
                ai = fmaf(f0[r].y, wi.y, ai);
                ai = fmaf(f0[r].z, wi.z, ai);
                ai = fmaf(f0[r].w, wi.w, ai);
                acc_i[r][a] = ai;
                float as = acc_s[r][a];
                as = fmaf(f1[r].x, ws.x, as);
                as = fmaf(f1[r].y, ws.y, as);
                as = fmaf(f1[r].z, ws.z, as);
                as = fmaf(f1[r].w, ws.w, as);
                acc_s[r][a] = as;
            }
        }
    }

    // ---- butterfly reduction: after this EVERY lane holds full sums ----
#pragma unroll
    for (int off = 32; off > 0; off >>= 1) {
#pragma unroll
        for (int r = 0; r < R; ++r)
#pragma unroll
            for (int a = 0; a < 9; ++a) {
                acc_i[r][a] += __shfl_xor(acc_i[r][a], off, 64);
                acc_s[r][a] += __shfl_xor(acc_s[r][a], off, 64);
            }
    }

    // ---- epilogue: lane = rr*9 + k handles (row r0+rr, output col k) ----
    int rr = lane / 9;
    const int k = lane - rr * 9;
    const bool active = (rr < R);
    if (!active) rr = 0;   // keep all 64 lanes in uniform control flow for shuffles

    // select this/last for my row from register arrays (no dynamic indexing)
    float thisv[9], lastv[9];
#pragma unroll
    for (int a = 0; a < 9; ++a) {
        float tv = acc_s[0][a], lv = acc_i[0][a];
        tv = (rr == 1) ? acc_s[1][a] : tv;  lv = (rr == 1) ? acc_i[1][a] : lv;
        tv = (rr == 2) ? acc_s[2][a] : tv;  lv = (rr == 2) ? acc_i[2][a] : lv;
        tv = (rr == 3) ? acc_s[3][a] : tv;  lv = (rr == 3) ? acc_i[3][a] : lv;
        thisv[a] = tv; lastv[a] = lv;
    }

    // bil[k] = sum_a sum_j this[a]*last[j]*trans[a][j][k]
    float bil = 0.f;
#pragma unroll
    for (int a = 0; a < 9; ++a) {
        const float ta = thisv[a];
#pragma unroll
        for (int j = 0; j < 9; ++j) {
            bil = fmaf(ta * lastv[j], sTr[a * 81 + j * 9 + k], bil);
        }
    }

    // gather all 9 bil values of my row (variable-lane shuffle = ds_bpermute)
    const int rbase = rr * 9;
    float bilv[9];
#pragma unroll
    for (int j = 0; j < 9; ++j) bilv[j] = __shfl(bil, rbase + j, 64);

    // LayerNorm(9)
    float mu = 0.f;
#pragma unroll
    for (int j = 0; j < 9; ++j) mu += bilv[j];
    mu *= (1.f / 9.f);
    float var = 0.f;
#pragma unroll
    for (int j = 0; j < 9; ++j) { const float d = bilv[j] - mu; var = fmaf(d, d, var); }
    var *= (1.f / 9.f);
    const float rs = rsqrtf(var + LN_EPS);

    // out[k] = b_out[k] + sum_a this[a]*W_out[k][a] + sum_j ln[j]*W_out[k][9+j]
    float o = sBo[k];
#pragma unroll
    for (int a = 0; a < 9; ++a) o = fmaf(thisv[a], sWo[k * 18 + a], o);
#pragma unroll
    for (int j = 0; j < 9; ++j) {
        const float lnj = fmaf((bilv[j] - mu) * rs, sLw[j], sLb[j]);
        o = fmaf(lnj, sWo[k * 18 + 9 + j], o);
    }

    const int row = r0 + rr;
    if (active && row < B) out[(size_t)row * 9 + k] = o;
}

extern "C" void kernel_launch(void* const* d_in, const int* in_sizes, int n_in,
                              void* d_out, int out_size, void* d_ws, size_t ws_size,
                              hipStream_t stream) {
    const float* feat   = (const float*)d_in[0];
    const float* W_int  = (const float*)d_in[1];
    const float* W_stim = (const float*)d_in[2];
    const float* trans  = (const float*)d_in[3];
    const float* ln_w   = (const float*)d_in[4];
    const float* ln_b   = (const float*)d_in[5];
    const float* W_out  = (const float*)d_in[6];
    const float* b_out  = (const float*)d_in[7];
    float* out = (float*)d_out;

    const int B = in_sizes[0] / (2 * DIM);             // 65536
    const int rows_per_block = WAVES * R;              // 32
    const int grid = (B + rows_per_block - 1) / rows_per_block;

    fused_concat_linear<<<grid, BLOCK, 0, stream>>>(
        feat, W_int, W_stim, trans, ln_w, ln_b, W_out, b_out, out, B);
}

// Round 2
// 560.977 us; speedup vs baseline: 1.0651x; 1.0651x over previous
//
#include <hip/hip_runtime.h>

#define LN_EPS 1e-5f

constexpr int DIM    = 768;
constexpr int NSPLIT = 4;              // waves per block; each covers DIM/NSPLIT
constexpr int BLOCK  = NSPLIT * 64;    // 256 threads
constexpr int SEG    = DIM / NSPLIT;   // 192 floats per wave
constexpr int C      = 32;             // chunk = 32 floats = 128 B = 1 cache line
constexpr int NCHUNK = SEG / C;        // 6

// Lane <-> row mapping; wave w accumulates partial dots over cols [w*SEG, (w+1)*SEG).
// No cross-lane shuffles anywhere: partials meet once in LDS, epilogue is per-lane.
__launch_bounds__(BLOCK, 4)   // cap VGPRs at 128 -> 4 waves/SIMD, 16 waves/CU
__global__ void fused_concat_linear(const float* __restrict__ feat,
                                    const float* __restrict__ W_int,
                                    const float* __restrict__ W_stim,
                                    const float* __restrict__ trans,
                                    const float* __restrict__ ln_w,
                                    const float* __restrict__ ln_b,
                                    const float* __restrict__ W_out,
                                    const float* __restrict__ b_out,
                                    float* __restrict__ out,
                                    int B)
{
    __shared__ float sP[NSPLIT][18][64];   // per-wave partial dots, 18.4 KB

    const int lane = threadIdx.x & 63;
    // pin wave index to an SGPR so weight addresses are provably wave-uniform -> s_load
    const int wave = __builtin_amdgcn_readfirstlane(threadIdx.x >> 6);

    const int row = blockIdx.x * 64 + lane;
    const int rr  = min(row, B - 1);
    const float* frow = feat + (size_t)rr * (2 * DIM);

    float accL[9], accT[9];
#pragma unroll
    for (int a = 0; a < 9; ++a) { accL[a] = 0.f; accT[a] = 0.f; }

#pragma unroll
    for (int ch = 0; ch < NCHUNK; ++ch) {
        const int c0 = wave * SEG + ch * C;   // 128-B aligned within the row

        // my row's slice: 8 float4 per feature = exactly one cache line each of
        // 4 lines; consecutive dwordx4 to the same line merge in flight -> 1x fetch
        float4 f0[8], f1[8];
#pragma unroll
        for (int m = 0; m < 8; ++m) f0[m] = *(const float4*)(frow + c0 + 4 * m);
#pragma unroll
        for (int m = 0; m < 8; ++m) f1[m] = *(const float4*)(frow + DIM + c0 + 4 * m);

#pragma unroll
        for (int a = 0; a < 9; ++a) {
            const float* wi = W_int  + a * DIM + c0;   // wave-uniform -> scalar loads
            const float* ws = W_stim + a * DIM + c0;
            float sL = accL[a];
#pragma unroll
            for (int m = 0; m < 8; ++m) {
                const float4 w = *(const float4*)(wi + 4 * m);
                sL = fmaf(f0[m].x, w.x, sL);
                sL = fmaf(f0[m].y, w.y, sL);
                sL = fmaf(f0[m].z, w.z, sL);
                sL = fmaf(f0[m].w, w.w, sL);
            }
            accL[a] = sL;
            float sT = accT[a];
#pragma unroll
            for (int m = 0; m < 8; ++m) {
                const float4 w = *(const float4*)(ws + 4 * m);
                sT = fmaf(f1[m].x, w.x, sT);
                sT = fmaf(f1[m].y, w.y, sT);
                sT = fmaf(f1[m].z, w.z, sT);
                sT = fmaf(f1[m].w, w.w, sT);
            }
            accT[a] = sT;
        }
    }

    // deposit partials: [wave][val][lane] -> lane-consecutive, conflict-free
#pragma unroll
    for (int a = 0; a < 9; ++a) {
        sP[wave][a][lane]     = accL[a];
        sP[wave][9 + a][lane] = accT[a];
    }
    __syncthreads();

    if (wave == 0) {
        // lane owns its row end-to-end; combine the 4 DIM-quarters
        float lastv[9], thisv[9];
#pragma unroll
        for (int a = 0; a < 9; ++a) {
            lastv[a] = ((sP[0][a][lane]     + sP[1][a][lane])
                      + (sP[2][a][lane]     + sP[3][a][lane]));
            thisv[a] = ((sP[0][9 + a][lane] + sP[1][9 + a][lane])
                      + (sP[2][9 + a][lane] + sP[3][9 + a][lane]));
        }

        // bil[k] = sum_{a,j} this[a]*last[j]*trans[a][j][k]  (trans: uniform scalar loads)
        float bil[9];
#pragma unroll
        for (int k = 0; k < 9; ++k) bil[k] = 0.f;
#pragma unroll
        for (int a = 0; a < 9; ++a) {
#pragma unroll
            for (int j = 0; j < 9; ++j) {
                const float p = thisv[a] * lastv[j];
                const float* tp = trans + (a * 81 + j * 9);
#pragma unroll
                for (int k = 0; k < 9; ++k) bil[k] = fmaf(p, tp[k], bil[k]);
            }
        }

        // LayerNorm(9)
        float mu = 0.f;
#pragma unroll
        for (int k = 0; k < 9; ++k) mu += bil[k];
        mu *= (1.f / 9.f);
        float var = 0.f;
#pragma unroll
        for (int k = 0; k < 9; ++k) { const float d = bil[k] - mu; var = fmaf(d, d, var); }
        var *= (1.f / 9.f);
        const float rs = rsqrtf(var + LN_EPS);

        float lnv[9];
#pragma unroll
        for (int j = 0; j < 9; ++j)
            lnv[j] = fmaf((bil[j] - mu) * rs, ln_w[j], ln_b[j]);

        // out[i] = b_out[i] + this . W_out[i][0:9] + ln . W_out[i][9:18]
        if (row < B) {
#pragma unroll
            for (int i = 0; i < 9; ++i) {
                float o = b_out[i];
#pragma unroll
                for (int a = 0; a < 9; ++a) o = fmaf(thisv[a], W_out[i * 18 + a], o);
#pragma unroll
                for (int j = 0; j < 9; ++j) o = fmaf(lnv[j], W_out[i * 18 + 9 + j], o);
                out[(size_t)row * 9 + i] = o;
            }
        }
    }
}

extern "C" void kernel_launch(void* const* d_in, const int* in_sizes, int n_in,
                              void* d_out, int out_size, void* d_ws, size_t ws_size,
                              hipStream_t stream) {
    const float* feat   = (const float*)d_in[0];
    const float* W_int  = (const float*)d_in[1];
    const float* W_stim = (const float*)d_in[2];
    const float* trans  = (const float*)d_in[3];
    const float* ln_w   = (const float*)d_in[4];
    const float* ln_b   = (const float*)d_in[5];
    const float* W_out  = (const float*)d_in[6];
    const float* b_out  = (const float*)d_in[7];
    float* out = (float*)d_out;

    const int B = in_sizes[0] / (2 * DIM);          // 65536
    const int grid = (B + 63) / 64;                 // 1024 blocks, 64 rows each

    fused_concat_linear<<<grid, BLOCK, 0, stream>>>(
        feat, W_int, W_stim, trans, ln_w, ln_b, W_out, b_out, out, B);
}